// Round 1
// baseline (1340.177 us; speedup 1.0000x reference)
//
#include <hip/hip_runtime.h>
#include <hip/hip_bf16.h>

typedef __attribute__((ext_vector_type(8))) short short8;
typedef __attribute__((ext_vector_type(4))) float f32x4;

__device__ __forceinline__ float bf2f(unsigned short u) {
    union { unsigned int i; float f; } v; v.i = ((unsigned int)u) << 16; return v.f;
}
__device__ __forceinline__ unsigned short f2bf(float f) {
    __hip_bfloat16 h = __float2bfloat16(f);
    union { __hip_bfloat16 h; unsigned short u; } v; v.h = h; return v.u;
}
__device__ __forceinline__ float gelu_exact(float t) {
    return 0.5f * t * (1.0f + erff(t * 0.70710678118654752f));
}

// ---------------------------------------------------------------------------
// Pre-transpose weights: Bt[n][k] (bf16, row-major [1152][128])
//   n in [0,1024): relation r = n>>7, dout = n&127 -> W[r][k][dout]
//   n in [1024,1152): dout = n-1024 -> root[k][dout]
// ---------------------------------------------------------------------------
__global__ void prep_w(const float* __restrict__ W, const float* __restrict__ root,
                       unsigned short* __restrict__ Bt) {
    int i = blockIdx.x * 256 + threadIdx.x;     // over 1152*128
    if (i >= 1152 * 128) return;
    int n = i >> 7, k = i & 127;
    float v;
    if (n < 1024) {
        int r = n >> 7, dout = n & 127;
        v = W[((size_t)r * 128 + k) * 128 + dout];
    } else {
        v = root[(size_t)k * 128 + (n - 1024)];
    }
    Bt[(size_t)n * 128 + k] = f2bf(v);
}

// ---------------------------------------------------------------------------
// LN + GELU on x (fp32 in) -> y (bf16 out). One wave per row, 2 elems/lane.
// ---------------------------------------------------------------------------
__global__ void ln_gelu(const float* __restrict__ x, const float* __restrict__ g,
                        const float* __restrict__ b, unsigned short* __restrict__ y, int N) {
    int row = (blockIdx.x * blockDim.x + threadIdx.x) >> 6;
    if (row >= N) return;
    int lane = threadIdx.x & 63;
    size_t off = (size_t)row * 128 + lane * 2;
    float2 v = *(const float2*)(x + off);
    float s = v.x + v.y;
    #pragma unroll
    for (int o = 32; o; o >>= 1) s += __shfl_xor(s, o);
    float mu = s * (1.0f / 128.0f);
    float d0 = v.x - mu, d1 = v.y - mu;
    float q = d0 * d0 + d1 * d1;
    #pragma unroll
    for (int o = 32; o; o >>= 1) q += __shfl_xor(q, o);
    float rs = rsqrtf(q * (1.0f / 128.0f) + 1e-5f);
    float2 gg = *(const float2*)(g + lane * 2);
    float2 bb = *(const float2*)(b + lane * 2);
    float t0 = gelu_exact(d0 * rs * gg.x + bb.x);
    float t1 = gelu_exact(d1 * rs * gg.y + bb.y);
    ushort2 o2; o2.x = f2bf(t0); o2.y = f2bf(t1);
    *(ushort2*)(y + off) = o2;
}

// ---------------------------------------------------------------------------
// out1 = agg + Hroot + bias; then LN(ln_g,ln_b) + GELU -> y (bf16)
// ---------------------------------------------------------------------------
__global__ void combine_ln_gelu(const float* __restrict__ agg, const float* __restrict__ Hroot,
                                const float* __restrict__ bias, const float* __restrict__ g,
                                const float* __restrict__ b, unsigned short* __restrict__ y, int N) {
    int row = (blockIdx.x * blockDim.x + threadIdx.x) >> 6;
    if (row >= N) return;
    int lane = threadIdx.x & 63;
    size_t off = (size_t)row * 128 + lane * 2;
    float2 va = *(const float2*)(agg + off);
    float2 vh = *(const float2*)(Hroot + off);
    float2 vb = *(const float2*)(bias + lane * 2);
    float t0 = va.x + vh.x + vb.x;
    float t1 = va.y + vh.y + vb.y;
    float s = t0 + t1;
    #pragma unroll
    for (int o = 32; o; o >>= 1) s += __shfl_xor(s, o);
    float mu = s * (1.0f / 128.0f);
    float d0 = t0 - mu, d1 = t1 - mu;
    float q = d0 * d0 + d1 * d1;
    #pragma unroll
    for (int o = 32; o; o >>= 1) q += __shfl_xor(q, o);
    float rs = rsqrtf(q * (1.0f / 128.0f) + 1e-5f);
    float2 gg = *(const float2*)(g + lane * 2);
    float2 bb = *(const float2*)(b + lane * 2);
    float u0 = gelu_exact(d0 * rs * gg.x + bb.x);
    float u1 = gelu_exact(d1 * rs * gg.y + bb.y);
    ushort2 o2; o2.x = f2bf(u0); o2.y = f2bf(u1);
    *(ushort2*)(y + off) = o2;
}

// ---------------------------------------------------------------------------
// GEMM: y [M x 128] bf16 row-major  @  Bt^T  (Bt is [1152 x 128] bf16 = B^T)
// -> Hrel bf16 [M x 1024] (cols 0..1023), Hroot fp32 [M x 128] (cols 1024..1151)
// Each wave computes a 16x64 strip via 4 n-tiles of 16x16, K=128 in 4 MFMA steps.
// mfma_f32_16x16x32_bf16: A lane l holds A[l&15][(l>>4)*8 + j]; B lane l holds
// B[(l>>4)*8+j][l&15] == Bt[l&15][(l>>4)*8+j]; C/D: col=lane&15, row=(lane>>4)*4+reg.
// ---------------------------------------------------------------------------
__global__ __launch_bounds__(256) void gemm_ws(const unsigned short* __restrict__ y,
                                               const unsigned short* __restrict__ Bt,
                                               unsigned short* __restrict__ Hrel,
                                               float* __restrict__ Hroot, int M) {
    int gw = (blockIdx.x * 256 + threadIdx.x) >> 6;
    int nWaves = (M / 16) * 18;            // 18 n-groups of 64 cols (1152/64)
    if (gw >= nWaves) return;
    int lane = threadIdx.x & 63;
    int mt = gw / 18, ng = gw % 18;
    int m0 = mt * 16, n0 = ng * 64;
    int arow = m0 + (lane & 15);
    int koff = (lane >> 4) * 8;
    const unsigned short* ya = y + (size_t)arow * 128 + koff;

    f32x4 acc[4] = {{0,0,0,0},{0,0,0,0},{0,0,0,0},{0,0,0,0}};
    #pragma unroll
    for (int kb = 0; kb < 4; ++kb) {
        short8 a = *(const short8*)(ya + kb * 32);
        #pragma unroll
        for (int t = 0; t < 4; ++t) {
            const unsigned short* bp = Bt + (size_t)(n0 + t * 16 + (lane & 15)) * 128 + kb * 32 + koff;
            short8 bfrag = *(const short8*)bp;
            acc[t] = __builtin_amdgcn_mfma_f32_16x16x32_bf16(a, bfrag, acc[t], 0, 0, 0);
        }
    }
    int rbase = m0 + ((lane >> 4) << 2);
    int cl = lane & 15;
    #pragma unroll
    for (int t = 0; t < 4; ++t) {
        int c = n0 + t * 16 + cl;
        #pragma unroll
        for (int reg = 0; reg < 4; ++reg) {
            int rrow = rbase + reg;
            float v = acc[t][reg];
            if (c < 1024) Hrel[(size_t)rrow * 1024 + c] = f2bf(v);
            else          Hroot[(size_t)rrow * 128 + (c - 1024)] = v;
        }
    }
}

// ---------------------------------------------------------------------------
// Zero fp32 buffer (grid-stride float4)
// ---------------------------------------------------------------------------
__global__ void zero_f4(float4* __restrict__ p, size_t n4) {
    size_t i = (size_t)blockIdx.x * blockDim.x + threadIdx.x;
    size_t stride = (size_t)gridDim.x * blockDim.x;
    float4 z = {0.f, 0.f, 0.f, 0.f};
    for (; i < n4; i += stride) p[i] = z;
}

// ---------------------------------------------------------------------------
// Edge kernel: one wave per edge.
// msg[d] = sum_r attr[e][r] * Hrel[src][r*128 + d];  atomicAdd into agg[dst][d].
// Lane handles cols {2*lane, 2*lane+1} -> loads 1 dword per relation (coalesced).
// ---------------------------------------------------------------------------
__global__ __launch_bounds__(256) void edge_agg(const int* __restrict__ ei,
                                                const float* __restrict__ attr,
                                                const unsigned short* __restrict__ Hrel,
                                                float* __restrict__ agg, int E) {
    int e = (blockIdx.x << 2) + (threadIdx.x >> 6);
    if (e >= E) return;
    int lane = threadIdx.x & 63;
    int src = ei[e];
    int dst = ei[E + e];
    const unsigned int* hp = (const unsigned int*)(Hrel + (size_t)src * 1024) + lane;
    float m0 = 0.f, m1 = 0.f;
    #pragma unroll
    for (int r = 0; r < 8; ++r) {
        float a = attr[(size_t)e * 8 + r];
        unsigned int h = hp[r * 64];
        m0 += a * bf2f((unsigned short)(h & 0xffffu));
        m1 += a * bf2f((unsigned short)(h >> 16));
    }
    float* ap = agg + (size_t)dst * 128 + lane * 2;
    atomicAdd(ap, m0);
    atomicAdd(ap + 1, m1);
}

// ---------------------------------------------------------------------------
// Final: out = agg + Hroot + b2 + x   (residual)
// ---------------------------------------------------------------------------
__global__ void final_add(const float* __restrict__ agg, const float* __restrict__ Hroot,
                          const float* __restrict__ bias, const float* __restrict__ x,
                          float* __restrict__ out, size_t n4) {
    size_t i = (size_t)blockIdx.x * blockDim.x + threadIdx.x;
    size_t stride = (size_t)gridDim.x * blockDim.x;
    for (; i < n4; i += stride) {
        float4 va = ((const float4*)agg)[i];
        float4 vh = ((const float4*)Hroot)[i];
        float4 vx = ((const float4*)x)[i];
        float4 vb = ((const float4*)bias)[i & 31];   // 128/4 = 32 float4 per row
        float4 o;
        o.x = va.x + vh.x + vx.x + vb.x;
        o.y = va.y + vh.y + vx.y + vb.y;
        o.z = va.z + vh.z + vx.z + vb.z;
        o.w = va.w + vh.w + vx.w + vb.w;
        ((float4*)out)[i] = o;
    }
}

extern "C" void kernel_launch(void* const* d_in, const int* in_sizes, int n_in,
                              void* d_out, int out_size, void* d_ws, size_t ws_size,
                              hipStream_t stream) {
    const float* x     = (const float*)d_in[0];
    const int*   ei    = (const int*)d_in[1];
    const float* attr  = (const float*)d_in[2];
    const float* ln1g  = (const float*)d_in[3];
    const float* ln1b  = (const float*)d_in[4];
    const float* W1    = (const float*)d_in[5];
    const float* root1 = (const float*)d_in[6];
    const float* b1    = (const float*)d_in[7];
    const float* ln2g  = (const float*)d_in[8];
    const float* ln2b  = (const float*)d_in[9];
    const float* W2    = (const float*)d_in[10];
    const float* root2 = (const float*)d_in[11];
    const float* b2    = (const float*)d_in[12];

    const int N = in_sizes[0] / 128;   // 50000
    const int E = in_sizes[1] / 2;     // 600000

    // workspace layout (aligned)
    char* ws = (char*)d_ws;
    unsigned short* y    = (unsigned short*)(ws);                       // N*128*2   = 12,800,000
    unsigned short* Hrel = (unsigned short*)(ws + 12800000);            // N*1024*2  = 102,400,000
    float*          Hroot= (float*)(ws + 115200000);                    // N*128*4   = 25,600,000
    float*          agg  = (float*)(ws + 140800000);                    // N*128*4   = 25,600,000
    unsigned short* Bt1  = (unsigned short*)(ws + 166400000);           // 294,912
    unsigned short* Bt2  = (unsigned short*)(ws + 166694912);           // 294,912

    const int rowsBlocks = (N * 64 + 255) / 256;          // wave-per-row kernels
    const int gemmWaves  = (N / 16) * 18;
    const int gemmBlocks = (gemmWaves + 3) / 4;
    const int edgeBlocks = (E + 3) / 4;
    const size_t n4      = (size_t)N * 32;

    // weights (must re-run every call: stateless)
    prep_w<<<576, 256, 0, stream>>>(W1, root1, Bt1);
    prep_w<<<576, 256, 0, stream>>>(W2, root2, Bt2);

    // ---- layer 1 ----
    ln_gelu<<<rowsBlocks, 256, 0, stream>>>(x, ln1g, ln1b, y, N);
    gemm_ws<<<gemmBlocks, 256, 0, stream>>>(y, Bt1, Hrel, Hroot, N);
    zero_f4<<<2048, 256, 0, stream>>>((float4*)agg, n4);
    edge_agg<<<edgeBlocks, 256, 0, stream>>>(ei, attr, Hrel, agg, E);

    // ---- layer 2 ----
    combine_ln_gelu<<<rowsBlocks, 256, 0, stream>>>(agg, Hroot, b1, ln2g, ln2b, y, N);
    gemm_ws<<<gemmBlocks, 256, 0, stream>>>(y, Bt2, Hrel, Hroot, N);
    zero_f4<<<2048, 256, 0, stream>>>((float4*)agg, n4);
    edge_agg<<<edgeBlocks, 256, 0, stream>>>(ei, attr, Hrel, agg, E);

    // ---- final residual add ----
    final_add<<<2048, 256, 0, stream>>>(agg, Hroot, b2, x, (float*)d_out, n4);
}

// Round 2
// 358.134 us; speedup vs baseline: 3.7421x; 3.7421x over previous
//
#include <hip/hip_runtime.h>
#include <hip/hip_bf16.h>

typedef __attribute__((ext_vector_type(8))) short short8;
typedef __attribute__((ext_vector_type(4))) float f32x4;

__device__ __forceinline__ float bf2f(unsigned short u) {
    union { unsigned int i; float f; } v; v.i = ((unsigned int)u) << 16; return v.f;
}
__device__ __forceinline__ unsigned short f2bf(float f) {
    __hip_bfloat16 h = __float2bfloat16(f);
    union { __hip_bfloat16 h; unsigned short u; } v; v.h = h; return v.u;
}
__device__ __forceinline__ float gelu_exact(float t) {
    return 0.5f * t * (1.0f + erff(t * 0.70710678118654752f));
}

// ---------------------------------------------------------------------------
// Pack B = vertcat(W[0..7], root)  [1152 x 128] into MFMA B-fragment order:
// frag idx = ((kb*8 + t)*64 + lane)*8 + j  holds B[kb*32 + (lane>>4)*8 + j][t*16 + (lane&15)]
// ---------------------------------------------------------------------------
__global__ void prep_w(const float* __restrict__ W, const float* __restrict__ root,
                       unsigned short* __restrict__ Bfrag) {
    int i = blockIdx.x * 256 + threadIdx.x;     // over 1152*128
    if (i >= 1152 * 128) return;
    int k = i >> 7, n = i & 127;
    float v = (k < 1024) ? W[((size_t)(k >> 7) * 128 + (k & 127)) * 128 + n]
                         : root[(size_t)(k - 1024) * 128 + n];
    int kb = k >> 5;
    int lanehi = (k >> 3) & 3;
    int j = k & 7;
    int t = n >> 4;
    int lane = (lanehi << 4) | (n & 15);
    Bfrag[(((size_t)(kb * 8 + t) * 64 + lane) << 3) + j] = f2bf(v);
}

// ---------------------------------------------------------------------------
// CSR build: zero, histogram, 2-level exclusive scan, scatter (+permuted attr)
// ---------------------------------------------------------------------------
__global__ void zero_i32(int* __restrict__ p, int n) {
    int i = blockIdx.x * 256 + threadIdx.x;
    if (i < n) p[i] = 0;
}

__global__ void hist_dst(const int* __restrict__ ei, int* __restrict__ cnt, int E) {
    int e = blockIdx.x * 256 + threadIdx.x;
    if (e >= E) return;
    atomicAdd(&cnt[ei[E + e]], 1);
}

// block-of-256 exclusive scan; part[i] = excl within block, bsum[blk] = block total
__global__ void scan1(const int* __restrict__ cnt, int* __restrict__ part,
                      int* __restrict__ bsum, int N) {
    int i = blockIdx.x * 256 + threadIdx.x;
    int v = (i < N) ? cnt[i] : 0;
    int lane = threadIdx.x & 63, wid = threadIdx.x >> 6;
    int s = v;
    #pragma unroll
    for (int off = 1; off < 64; off <<= 1) {
        int t = __shfl_up(s, off);
        if (lane >= off) s += t;
    }
    __shared__ int wsum[4];
    if (lane == 63) wsum[wid] = s;
    __syncthreads();
    int add = 0;
    for (int w = 0; w < wid; ++w) add += wsum[w];
    s += add;
    part[i] = s - v;
    if (threadIdx.x == 255) bsum[blockIdx.x] = s;
}

// single-block exclusive scan of bsum[nb] in place (nb <= 256)
__global__ void scan2(int* __restrict__ bsum, int nb) {
    int i = threadIdx.x;
    int v = (i < nb) ? bsum[i] : 0;
    int lane = threadIdx.x & 63, wid = threadIdx.x >> 6;
    int s = v;
    #pragma unroll
    for (int off = 1; off < 64; off <<= 1) {
        int t = __shfl_up(s, off);
        if (lane >= off) s += t;
    }
    __shared__ int wsum[4];
    if (lane == 63) wsum[wid] = s;
    __syncthreads();
    int add = 0;
    for (int w = 0; w < wid; ++w) add += wsum[w];
    s += add;
    if (i < nb) bsum[i] = s - v;
}

__global__ void scan3(const int* __restrict__ part, const int* __restrict__ bsum,
                      int* __restrict__ rowptr, int* __restrict__ woff, int N) {
    int i = blockIdx.x * 256 + threadIdx.x;
    if (i >= N) return;
    int v = part[i] + bsum[blockIdx.x];
    rowptr[i] = v;
    woff[i] = v;
}

__global__ void scatter_edges(const int* __restrict__ ei, const float4* __restrict__ attr,
                              int* __restrict__ woff, int* __restrict__ esrc,
                              float4* __restrict__ eattr, int E) {
    int e = blockIdx.x * 256 + threadIdx.x;
    if (e >= E) return;
    int src = ei[e], dst = ei[E + e];
    int p = atomicAdd(&woff[dst], 1);
    esrc[p] = src;
    eattr[2 * p]     = attr[2 * e];
    eattr[2 * p + 1] = attr[2 * e + 1];
}

// ---------------------------------------------------------------------------
// LN + GELU on x (fp32 in) -> y (bf16 out). One wave per row.
// ---------------------------------------------------------------------------
__global__ void ln_gelu(const float* __restrict__ x, const float* __restrict__ g,
                        const float* __restrict__ b, unsigned short* __restrict__ y, int N) {
    int row = (blockIdx.x * blockDim.x + threadIdx.x) >> 6;
    if (row >= N) return;
    int lane = threadIdx.x & 63;
    size_t off = (size_t)row * 128 + lane * 2;
    float2 v = *(const float2*)(x + off);
    float s = v.x + v.y;
    #pragma unroll
    for (int o = 32; o; o >>= 1) s += __shfl_xor(s, o);
    float mu = s * (1.0f / 128.0f);
    float d0 = v.x - mu, d1 = v.y - mu;
    float q = d0 * d0 + d1 * d1;
    #pragma unroll
    for (int o = 32; o; o >>= 1) q += __shfl_xor(q, o);
    float rs = rsqrtf(q * (1.0f / 128.0f) + 1e-5f);
    float2 gg = *(const float2*)(g + lane * 2);
    float2 bb = *(const float2*)(b + lane * 2);
    ushort2 o2;
    o2.x = f2bf(gelu_exact(d0 * rs * gg.x + bb.x));
    o2.y = f2bf(gelu_exact(d1 * rs * gg.y + bb.y));
    *(ushort2*)(y + off) = o2;
}

// ---------------------------------------------------------------------------
// Edge aggregation into z: one wave per dst node (CSR), register accumulation.
// z[v][r*128 + d] = sum_{e: dst=v} attr[e][r] * y[src_e][d]    (bf16 out)
// Lane handles cols {2*lane, 2*lane+1}.
// ---------------------------------------------------------------------------
__global__ __launch_bounds__(256) void edge_z(const int* __restrict__ rowptr,
                                              const int* __restrict__ esrc,
                                              const float4* __restrict__ eattr,
                                              const unsigned short* __restrict__ y,
                                              unsigned short* __restrict__ z, int N, int E) {
    int row = (blockIdx.x << 2) + (threadIdx.x >> 6);
    if (row >= N) return;
    int lane = threadIdx.x & 63;
    int e0 = rowptr[row];
    int e1 = (row + 1 < N) ? rowptr[row + 1] : E;
    float a00 = 0.f, a01 = 0.f, a10 = 0.f, a11 = 0.f, a20 = 0.f, a21 = 0.f, a30 = 0.f, a31 = 0.f;
    float a40 = 0.f, a41 = 0.f, a50 = 0.f, a51 = 0.f, a60 = 0.f, a61 = 0.f, a70 = 0.f, a71 = 0.f;
    for (int e = e0; e < e1; ++e) {
        int src = esrc[e];
        float4 w0 = eattr[2 * e];
        float4 w1 = eattr[2 * e + 1];
        unsigned int h = *(const unsigned int*)(y + (size_t)src * 128 + lane * 2);
        float y0 = bf2f((unsigned short)(h & 0xffffu));
        float y1 = bf2f((unsigned short)(h >> 16));
        a00 += w0.x * y0; a01 += w0.x * y1;
        a10 += w0.y * y0; a11 += w0.y * y1;
        a20 += w0.z * y0; a21 += w0.z * y1;
        a30 += w0.w * y0; a31 += w0.w * y1;
        a40 += w1.x * y0; a41 += w1.x * y1;
        a50 += w1.y * y0; a51 += w1.y * y1;
        a60 += w1.z * y0; a61 += w1.z * y1;
        a70 += w1.w * y0; a71 += w1.w * y1;
    }
    unsigned short* zr = z + (size_t)row * 1024 + lane * 2;
    ushort2 o;
    o.x = f2bf(a00); o.y = f2bf(a01); *(ushort2*)(zr + 0 * 128) = o;
    o.x = f2bf(a10); o.y = f2bf(a11); *(ushort2*)(zr + 1 * 128) = o;
    o.x = f2bf(a20); o.y = f2bf(a21); *(ushort2*)(zr + 2 * 128) = o;
    o.x = f2bf(a30); o.y = f2bf(a31); *(ushort2*)(zr + 3 * 128) = o;
    o.x = f2bf(a40); o.y = f2bf(a41); *(ushort2*)(zr + 4 * 128) = o;
    o.x = f2bf(a50); o.y = f2bf(a51); *(ushort2*)(zr + 5 * 128) = o;
    o.x = f2bf(a60); o.y = f2bf(a61); *(ushort2*)(zr + 6 * 128) = o;
    o.x = f2bf(a70); o.y = f2bf(a71); *(ushort2*)(zr + 7 * 128) = o;
}

// ---------------------------------------------------------------------------
// Fused GEMM: C = [z | y] (N x 1152) @ B (1152 x 128), one wave per 16 rows.
// MODE 0: out = gelu(LN(C + bias; lng, lnb)) -> bf16 y2
// MODE 1: out = C + bias + x -> fp32 (final residual)
// A-frag: lane holds A[m0+(l&15)][kb*32 + (l>>4)*8 + j]
// B-frag: pre-packed by prep_w (lane-contiguous 16B loads)
// C/D: col = t*16 + (lane&15), row = m0 + (lane>>4)*4 + reg
// ---------------------------------------------------------------------------
template <int MODE>
__global__ __launch_bounds__(256) void gemm_fused(
        const unsigned short* __restrict__ z, const unsigned short* __restrict__ y,
        const unsigned short* __restrict__ Bfrag, const float* __restrict__ bias,
        const float* __restrict__ lng, const float* __restrict__ lnb,
        const float* __restrict__ xres, void* __restrict__ outp, int N) {
    int gw = (blockIdx.x * 256 + threadIdx.x) >> 6;
    int nTiles = N >> 4;
    if (gw >= nTiles) return;
    int lane = threadIdx.x & 63;
    int l15 = lane & 15, lhi = lane >> 4;
    int m0 = gw << 4;
    int koff = lhi * 8;
    const unsigned short* za = z + (size_t)(m0 + l15) * 1024 + koff;
    const unsigned short* ya = y + (size_t)(m0 + l15) * 128 + koff;
    const short8* bf = (const short8*)Bfrag + lane;

    f32x4 acc[8] = {};
    #pragma unroll 4
    for (int kb = 0; kb < 32; ++kb) {
        short8 a = *(const short8*)(za + kb * 32);
        #pragma unroll
        for (int t = 0; t < 8; ++t) {
            short8 b = bf[(kb * 8 + t) * 64];
            acc[t] = __builtin_amdgcn_mfma_f32_16x16x32_bf16(a, b, acc[t], 0, 0, 0);
        }
    }
    #pragma unroll
    for (int kb = 32; kb < 36; ++kb) {
        short8 a = *(const short8*)(ya + (kb - 32) * 32);
        #pragma unroll
        for (int t = 0; t < 8; ++t) {
            short8 b = bf[(kb * 8 + t) * 64];
            acc[t] = __builtin_amdgcn_mfma_f32_16x16x32_bf16(a, b, acc[t], 0, 0, 0);
        }
    }

    float bcol[8];
    #pragma unroll
    for (int t = 0; t < 8; ++t) bcol[t] = bias[t * 16 + l15];

    if (MODE == 0) {
        float gcol[8], lbcol[8];
        #pragma unroll
        for (int t = 0; t < 8; ++t) { gcol[t] = lng[t * 16 + l15]; lbcol[t] = lnb[t * 16 + l15]; }
        unsigned short* y2 = (unsigned short*)outp;
        #pragma unroll
        for (int reg = 0; reg < 4; ++reg) {
            int row = m0 + lhi * 4 + reg;
            float tv[8];
            float s = 0.f;
            #pragma unroll
            for (int t = 0; t < 8; ++t) { tv[t] = acc[t][reg] + bcol[t]; s += tv[t]; }
            #pragma unroll
            for (int msk = 1; msk < 16; msk <<= 1) s += __shfl_xor(s, msk);
            float mu = s * (1.0f / 128.0f);
            float q = 0.f;
            #pragma unroll
            for (int t = 0; t < 8; ++t) { float d = tv[t] - mu; q += d * d; }
            #pragma unroll
            for (int msk = 1; msk < 16; msk <<= 1) q += __shfl_xor(q, msk);
            float rs = rsqrtf(q * (1.0f / 128.0f) + 1e-5f);
            #pragma unroll
            for (int t = 0; t < 8; ++t) {
                float u = gelu_exact((tv[t] - mu) * rs * gcol[t] + lbcol[t]);
                y2[(size_t)row * 128 + t * 16 + l15] = f2bf(u);
            }
        }
    } else {
        float* out = (float*)outp;
        #pragma unroll
        for (int reg = 0; reg < 4; ++reg) {
            int row = m0 + lhi * 4 + reg;
            #pragma unroll
            for (int t = 0; t < 8; ++t) {
                size_t idx = (size_t)row * 128 + t * 16 + l15;
                out[idx] = acc[t][reg] + bcol[t] + xres[idx];
            }
        }
    }
}

extern "C" void kernel_launch(void* const* d_in, const int* in_sizes, int n_in,
                              void* d_out, int out_size, void* d_ws, size_t ws_size,
                              hipStream_t stream) {
    const float* x     = (const float*)d_in[0];
    const int*   ei    = (const int*)d_in[1];
    const float* attr  = (const float*)d_in[2];
    const float* ln1g  = (const float*)d_in[3];
    const float* ln1b  = (const float*)d_in[4];
    const float* W1    = (const float*)d_in[5];
    const float* root1 = (const float*)d_in[6];
    const float* b1    = (const float*)d_in[7];
    const float* ln2g  = (const float*)d_in[8];
    const float* ln2b  = (const float*)d_in[9];
    const float* W2    = (const float*)d_in[10];
    const float* root2 = (const float*)d_in[11];
    const float* b2    = (const float*)d_in[12];

    const int N = in_sizes[0] / 128;   // 50000
    const int E = in_sizes[1] / 2;     // 600000

    char* ws = (char*)d_ws;
    unsigned short* y1    = (unsigned short*)(ws);                    // 12,800,000
    unsigned short* y2    = (unsigned short*)(ws + 12800000);         // 12,800,000
    unsigned short* z     = (unsigned short*)(ws + 25600000);         // 102,400,000
    unsigned short* Bf1   = (unsigned short*)(ws + 128000000);        // 294,912
    unsigned short* Bf2   = (unsigned short*)(ws + 128294912);        // 294,912
    int*            cnt   = (int*)(ws + 128589824);                   // 200,704
    int*            part  = (int*)(ws + 128790528);                   // 200,704
    int*            bsum  = (int*)(ws + 128991232);                   // 1,024
    int*            rowptr= (int*)(ws + 128992256);                   // 200,000
    int*            woff  = (int*)(ws + 129192256);                   // 200,000
    int*            esrc  = (int*)(ws + 129392256);                   // 2,400,000
    float4*         eattr = (float4*)(ws + 131792256);                // 19,200,000

    const int scanBlocks  = (N + 255) / 256;               // 196
    const int edgeBlocksE = (E + 255) / 256;               // 2344
    const int rowsBlocks  = (N * 64 + 255) / 256;          // 12500
    const int nodeBlocks  = (N + 3) / 4;                   // 12500
    const int gemmBlocks  = ((N >> 4) + 3) / 4;            // 782

    // weights -> fragment order
    prep_w<<<576, 256, 0, stream>>>(W1, root1, Bf1);
    prep_w<<<576, 256, 0, stream>>>(W2, root2, Bf2);

    // CSR build (by dst)
    zero_i32<<<scanBlocks, 256, 0, stream>>>(cnt, scanBlocks * 256);
    hist_dst<<<edgeBlocksE, 256, 0, stream>>>(ei, cnt, E);
    scan1<<<scanBlocks, 256, 0, stream>>>(cnt, part, bsum, N);
    scan2<<<1, 256, 0, stream>>>(bsum, scanBlocks);
    scan3<<<scanBlocks, 256, 0, stream>>>(part, bsum, rowptr, woff, N);
    scatter_edges<<<edgeBlocksE, 256, 0, stream>>>(ei, (const float4*)attr, woff, esrc, eattr, E);

    // ---- layer 1 ----
    ln_gelu<<<rowsBlocks, 256, 0, stream>>>(x, ln1g, ln1b, y1, N);
    edge_z<<<nodeBlocks, 256, 0, stream>>>(rowptr, esrc, eattr, y1, z, N, E);
    gemm_fused<0><<<gemmBlocks, 256, 0, stream>>>(z, y1, Bf1, b1, ln2g, ln2b, nullptr, (void*)y2, N);

    // ---- layer 2 ----
    edge_z<<<nodeBlocks, 256, 0, stream>>>(rowptr, esrc, eattr, y2, z, N, E);
    gemm_fused<1><<<gemmBlocks, 256, 0, stream>>>(z, y2, Bf2, b2, nullptr, nullptr, x, d_out, N);
}